// Round 5
// baseline (619.907 us; speedup 1.0000x reference)
//
#include <hip/hip_runtime.h>

constexpr int K = 128;   // states
constexpr int T = 512;   // timesteps
constexpr int NB = 16;   // batch columns per block

typedef __attribute__((ext_vector_type(8))) short short8;  // mfma A/B frag
typedef __attribute__((ext_vector_type(4))) float f32x4;   // mfma C/D frag

// s_barrier WITHOUT the compiler's vmcnt(0) drain (LDS-only wait).
__device__ __forceinline__ void bar_lgkm() {
  asm volatile("s_waitcnt lgkmcnt(0)\n\ts_barrier" ::: "memory");
}
// pack two fp32 -> bf16x2 (round-half-up; bias < 2^-16 rel, fine here)
__device__ __forceinline__ unsigned bfpair(float a, float b) {
  unsigned ua = __float_as_uint(a) + 0x8000u;
  unsigned ub = __float_as_uint(b) + 0x8000u;
  return (ua >> 16) | (ub & 0xFFFF0000u);
}
__device__ __forceinline__ float bf2f(short v) {
  return __uint_as_float(((unsigned)(unsigned short)v) << 16);
}
union pk_u { int4 i; short8 s; };

// One block = 16 batch rows, 128 threads (2 waves). Per step:
//   C(128x16) = E(128x128,bf16 A-frags) @ P(128x16,bf16 B-frags in LDS)
//   P'[j,b] = C[j,b] * exp(h[b,t,j]) * exp(S_b - S'_b)     (linear domain)
// Per-column freeze at len_b via select against register-held old values.
// One barrier per step; P and S double-buffered.
__global__ __launch_bounds__(128, 1)
void crf_fwd(const float* __restrict__ h, const float* __restrict__ trans,
             const float* __restrict__ mask, float* __restrict__ out) {
  const int tid  = threadIdx.x;
  const int lane = tid & 63;
  const int w    = tid >> 6;       // wave 0/1: owns j-strips 4w..4w+3
  const int q    = lane >> 4;      // quad id 0..3
  const int b    = lane & 15;      // batch column (and A-frag row m)
  const int boff = blockIdx.x * NB;

  __shared__ __align__(16) short bfrag[2][4 * 64 * 8]; // [buf][(c*64+lane)*8+i]
  __shared__ float S_lds[2][NB];                       // shift tracker, dbuf
  __shared__ float sigma[NB];                          // final shift per column
  __shared__ float lenp[NB][8];
  __shared__ float red[NB * 16];

  // ---- A fragments: E[j,k] = exp(trans[j,k]) in mfma A layout ----
  // strip s = 4w+ss covers rows j = 16s..16s+15; frag lane (m=b, q):
  // elem i of A[ss][c] = E[16s+b][32c+8q+i]
  short8 A[4][4];
  #pragma unroll
  for (int ss = 0; ss < 4; ++ss) {
    const float* rowp = trans + (size_t)(16 * (4 * w + ss) + b) * K + 8 * q;
    #pragma unroll
    for (int c = 0; c < 4; ++c) {
      const float4* f4 = reinterpret_cast<const float4*>(rowp + 32 * c);
      float4 x = f4[0], y = f4[1];
      pk_u u;
      u.i.x = bfpair(__expf(x.x), __expf(x.y));
      u.i.y = bfpair(__expf(x.z), __expf(x.w));
      u.i.z = bfpair(__expf(y.x), __expf(y.y));
      u.i.w = bfpair(__expf(y.z), __expf(y.w));
      A[ss][c] = u.s;
    }
  }

  // ---- len partials: thread (lb=tid>>3, seg=tid&7) sums 64 mask floats ----
  {
    const int lb = tid >> 3, seg = tid & 7;
    const float4* mp = reinterpret_cast<const float4*>(
        mask + (size_t)(boff + lb) * T + seg * 64);
    float s = 0.f;
    #pragma unroll
    for (int i = 0; i < 16; ++i) { float4 v = mp[i]; s += (v.x + v.y) + (v.z + v.w); }
    lenp[lb][seg] = s;
  }
  // zero P buffer 0 (4 KB, 32 B/thread)
  {
    int4 z = {0, 0, 0, 0};
    int4* dst = reinterpret_cast<int4*>(&bfrag[0][0]) + tid * 2;
    dst[0] = z; dst[1] = z;
  }
  if (tid < NB) { S_lds[0][tid] = 0.f; S_lds[1][tid] = 0.f; }
  bar_lgkm();
  if (tid < NB) {
    float s = 0.f;
    #pragma unroll
    for (int i = 0; i < 8; ++i) s += lenp[tid][i];
    red[tid] = s;                        // len_b
    bfrag[0][tid * 8] = (short)0x3F80;   // P(0): one-hot at k=SOS=0, col tid
  }
  bar_lgkm();

  const int lenv = (int)(red[b] + 0.5f);
  float mxf = red[0];
  #pragma unroll
  for (int i = 1; i < 16; ++i) mxf = fmaxf(mxf, red[i]);
  const int tmax = (int)(mxf + 0.5f);

  // ---- h prefetch (2 deep), exp applied at load ----
  const float* hbase = h + (size_t)(boff + b) * T * K;
  float4 ehc[4], ehn[4];
  #pragma unroll
  for (int ss = 0; ss < 4; ++ss) {
    const int j0 = 16 * (4 * w + ss) + 4 * q;
    float4 r0 = *reinterpret_cast<const float4*>(hbase + j0);   // t=0, len>=1
    ehc[ss] = make_float4(__expf(r0.x), __expf(r0.y), __expf(r0.z), __expf(r0.w));
    float4 r1 = (1 < lenv) ? *reinterpret_cast<const float4*>(hbase + K + j0)
                           : make_float4(0.f, 0.f, 0.f, 0.f);
    ehn[ss] = make_float4(__expf(r1.x), __expf(r1.y), __expf(r1.z), __expf(r1.w));
  }

  // per-strip write offsets into B-frag layout (shorts):
  // j0 = 16s+4q -> chunk c'=s>>1, lane' = (2*(s&1)+(q>>1))*16 + b, elem 4*(q&1)
  int widx[4];
  #pragma unroll
  for (int ss = 0; ss < 4; ++ss) {
    const int s = 4 * w + ss;
    const int lw = (2 * (s & 1) + (q >> 1)) * 16 + b;
    widx[ss] = (((s >> 1) * 64 + lw) * 8) + 4 * (q & 1);
  }

  float S = 0.f;                 // shift of current P (per column b)
  unsigned pold[4][2] = {{0u,0u},{0u,0u},{0u,0u},{0u,0u}};

  for (int t = 0; t < tmax; ++t) {
    const int rp = t & 1;
    bar_lgkm();                                    // P(t), S' now visible

    const short8* bp = reinterpret_cast<const short8*>(&bfrag[rp][0]);
    short8 B0 = bp[0 * 64 + lane];
    short8 B1 = bp[1 * 64 + lane];
    short8 B2 = bp[2 * 64 + lane];
    short8 B3 = bp[3 * 64 + lane];
    const float Sp = S_lds[rp][b];                 // S_{t+1} (stale tracker)

    f32x4 C0 = {0.f,0.f,0.f,0.f}, C1 = {0.f,0.f,0.f,0.f},
          C2 = {0.f,0.f,0.f,0.f}, C3 = {0.f,0.f,0.f,0.f};
    C0 = __builtin_amdgcn_mfma_f32_16x16x32_bf16(A[0][0], B0, C0, 0, 0, 0);
    C1 = __builtin_amdgcn_mfma_f32_16x16x32_bf16(A[1][0], B0, C1, 0, 0, 0);
    C2 = __builtin_amdgcn_mfma_f32_16x16x32_bf16(A[2][0], B0, C2, 0, 0, 0);
    C3 = __builtin_amdgcn_mfma_f32_16x16x32_bf16(A[3][0], B0, C3, 0, 0, 0);
    C0 = __builtin_amdgcn_mfma_f32_16x16x32_bf16(A[0][1], B1, C0, 0, 0, 0);
    C1 = __builtin_amdgcn_mfma_f32_16x16x32_bf16(A[1][1], B1, C1, 0, 0, 0);
    C2 = __builtin_amdgcn_mfma_f32_16x16x32_bf16(A[2][1], B1, C2, 0, 0, 0);
    C3 = __builtin_amdgcn_mfma_f32_16x16x32_bf16(A[3][1], B1, C3, 0, 0, 0);
    C0 = __builtin_amdgcn_mfma_f32_16x16x32_bf16(A[0][2], B2, C0, 0, 0, 0);
    C1 = __builtin_amdgcn_mfma_f32_16x16x32_bf16(A[1][2], B2, C1, 0, 0, 0);
    C2 = __builtin_amdgcn_mfma_f32_16x16x32_bf16(A[2][2], B2, C2, 0, 0, 0);
    C3 = __builtin_amdgcn_mfma_f32_16x16x32_bf16(A[3][2], B2, C3, 0, 0, 0);
    C0 = __builtin_amdgcn_mfma_f32_16x16x32_bf16(A[0][3], B3, C0, 0, 0, 0);
    C1 = __builtin_amdgcn_mfma_f32_16x16x32_bf16(A[1][3], B3, C1, 0, 0, 0);
    C2 = __builtin_amdgcn_mfma_f32_16x16x32_bf16(A[2][3], B3, C2, 0, 0, 0);
    C3 = __builtin_amdgcn_mfma_f32_16x16x32_bf16(A[3][3], B3, C3, 0, 0, 0);

    const bool act = (t < lenv);
    const float es = __expf(S - Sp);               // exp(S_t - S_{t+1}), per column

    short* wbuf = &bfrag[rp ^ 1][0];
#define EMIT(ss, Cv)                                                        \
    {                                                                       \
      float n0 = Cv[0] * ehc[ss].x * es, n1 = Cv[1] * ehc[ss].y * es;       \
      float n2 = Cv[2] * ehc[ss].z * es, n3 = Cv[3] * ehc[ss].w * es;       \
      unsigned w0 = bfpair(n0, n1), w1 = bfpair(n2, n3);                    \
      w0 = act ? w0 : pold[ss][0];                                          \
      w1 = act ? w1 : pold[ss][1];                                          \
      pold[ss][0] = w0; pold[ss][1] = w1;                                   \
      *reinterpret_cast<int2*>(wbuf + widx[ss]) = make_int2((int)w0, (int)w1); \
    }
    EMIT(0, C0) EMIT(1, C1) EMIT(2, C2) EMIT(3, C3)
#undef EMIT

    // tracker: state j=2 lives in wave 0, strip 0, q=0, reg 2
    if (w == 0 && q == 0) {
      float fs2 = __logf(ehc[0].z) + S + __logf(C0[2]);  // score_2 after step t
      S_lds[rp ^ 1][b] = act ? fs2 : S;
    }
    S = act ? Sp : S;

    // rotate h prefetch, issue t+2
    #pragma unroll
    for (int ss = 0; ss < 4; ++ss) ehc[ss] = ehn[ss];
    if (t + 2 < lenv) {
      #pragma unroll
      for (int ss = 0; ss < 4; ++ss) {
        const int j0 = 16 * (4 * w + ss) + 4 * q;
        float4 r = *reinterpret_cast<const float4*>(hbase + (size_t)(t + 2) * K + j0);
        ehn[ss] = make_float4(__expf(r.x), __expf(r.y), __expf(r.z), __expf(r.w));
      }
    }
  }

  // ---- epilogue: out[b] = sigma_b + log(sum_j P[j,b] * exp(trans[EOS,j])) ----
  if (w == 0 && q == 0) sigma[b] = S;       // lanes 0..15: b = lane
  bar_lgkm();
  const int rpf = tmax & 1;
  #pragma unroll
  for (int rep = 0; rep < 2; ++rep) {
    const int idx = tid + 128 * rep;
    const int bb = idx & 15, kg = idx >> 4;           // j-group: j = 8kg..8kg+7
    const int c = kg >> 2, ln = (kg & 3) * 16 + bb;
    const short8 pv = *reinterpret_cast<const short8*>(&bfrag[rpf][(c * 64 + ln) * 8]);
    const float* tre = trans + K + 8 * kg;            // trans[EOS=1][8kg..]
    float4 t0 = *reinterpret_cast<const float4*>(tre);
    float4 t1 = *reinterpret_cast<const float4*>(tre + 4);
    float acc = bf2f(pv[0]) * __expf(t0.x) + bf2f(pv[1]) * __expf(t0.y)
              + bf2f(pv[2]) * __expf(t0.z) + bf2f(pv[3]) * __expf(t0.w)
              + bf2f(pv[4]) * __expf(t1.x) + bf2f(pv[5]) * __expf(t1.y)
              + bf2f(pv[6]) * __expf(t1.z) + bf2f(pv[7]) * __expf(t1.w);
    red[bb * 16 + kg] = acc;
  }
  bar_lgkm();
  if (tid < NB) {
    float s = 0.f;
    #pragma unroll
    for (int i = 0; i < 16; ++i) s += red[tid * 16 + i];
    out[boff + tid] = sigma[tid] + __logf(s);
  }
}

extern "C" void kernel_launch(void* const* d_in, const int* in_sizes, int n_in,
                              void* d_out, int out_size, void* d_ws, size_t ws_size,
                              hipStream_t stream) {
  const float* h     = (const float*)d_in[0];  // (B,T,K) fp32
  const float* trans = (const float*)d_in[1];  // (K,K)   fp32
  const float* mask  = (const float*)d_in[2];  // (B,T)   fp32
  float* out = (float*)d_out;                  // (B,)    fp32
  const int B = in_sizes[0] / (T * K);         // 256
  crf_fwd<<<B / NB, 128, 0, stream>>>(h, trans, mask, out);
}

// Round 7
// 465.559 us; speedup vs baseline: 1.3315x; 1.3315x over previous
//
#include <hip/hip_runtime.h>

constexpr int K = 128;   // states
constexpr int T = 512;   // timesteps
constexpr int NB = 16;   // batch columns per block

typedef __attribute__((ext_vector_type(8))) short short8;  // mfma A/B frag
typedef __attribute__((ext_vector_type(4))) float f32x4;   // mfma C/D frag

// s_barrier WITHOUT the compiler's vmcnt(0) drain (LDS-only wait).
__device__ __forceinline__ void bar_lgkm() {
  asm volatile("s_waitcnt lgkmcnt(0)\n\ts_barrier" ::: "memory");
}
// pack two fp32 -> bf16x2 (round-half-up)
__device__ __forceinline__ unsigned bfpair(float a, float b) {
  unsigned ua = __float_as_uint(a) + 0x8000u;
  unsigned ub = __float_as_uint(b) + 0x8000u;
  return (ua >> 16) | (ub & 0xFFFF0000u);
}
__device__ __forceinline__ float bf2f(short v) {
  return __uint_as_float(((unsigned)(unsigned short)v) << 16);
}
union pk_u { int4 i; short8 s; };

// One block = 16 batch rows, 512 threads (8 waves). Wave w owns j-strip
// rows 16w..16w+15. Per step: C(16x16) = E_strip @ P (4 chained mfma),
// P'[j,b] = C * exp(h) * exp(S_b - S'_b), per-column freeze at len_b.
// h prefetched 4 deep in registers, exp deferred 1 iter (hides HBM latency).
__global__ __launch_bounds__(512, 1)
void crf_fwd(const float* __restrict__ h, const float* __restrict__ trans,
             const float* __restrict__ mask, float* __restrict__ out) {
  const int tid  = threadIdx.x;
  const int lane = tid & 63;
  const int w    = tid >> 6;       // wave id = j-strip 0..7
  const int q    = lane >> 4;      // quad 0..3
  const int b    = lane & 15;      // batch column
  const int boff = blockIdx.x * NB;

  __shared__ __align__(16) short bfrag[2][4 * 64 * 8]; // [buf][(c*64+lane)*8+i]
  __shared__ float S_lds[2][NB];                       // shift tracker, dbuf
  __shared__ float sigma[NB];
  __shared__ float lenp[NB][8];
  __shared__ float red[NB * 16];

  // ---- A fragments for strip w: elem i of A_c = exp(trans[16w+b][32c+8q+i])
  const float* rowp = trans + (size_t)(16 * w + b) * K + 8 * q;
  short8 A0, A1, A2, A3;
#define LDA(c, dst) { \
    const float4* f4 = reinterpret_cast<const float4*>(rowp + 32 * c); \
    float4 x = f4[0], y = f4[1]; pk_u u; \
    u.i.x = bfpair(__expf(x.x), __expf(x.y)); \
    u.i.y = bfpair(__expf(x.z), __expf(x.w)); \
    u.i.z = bfpair(__expf(y.x), __expf(y.y)); \
    u.i.w = bfpair(__expf(y.z), __expf(y.w)); \
    dst = u.s; }
  LDA(0, A0) LDA(1, A1) LDA(2, A2) LDA(3, A3)
#undef LDA

  // ---- len partials: threads 0..127, (lb, seg) sums 64 mask floats ----
  if (tid < 128) {
    const int lb = tid >> 3, seg = tid & 7;
    const float4* mp = reinterpret_cast<const float4*>(
        mask + (size_t)(boff + lb) * T + seg * 64);
    float s = 0.f;
    #pragma unroll
    for (int i = 0; i < 16; ++i) { float4 v = mp[i]; s += (v.x + v.y) + (v.z + v.w); }
    lenp[lb][seg] = s;
  }
  // zero BOTH P buffers (512 threads x 16B = 8 KB exact)
  { int4 z = {0, 0, 0, 0}; reinterpret_cast<int4*>(&bfrag[0][0])[tid] = z; }
  if (tid < NB) { S_lds[0][tid] = 0.f; S_lds[1][tid] = 0.f; }
  bar_lgkm();
  if (tid < NB) {
    float s = 0.f;
    #pragma unroll
    for (int i = 0; i < 8; ++i) s += lenp[tid][i];
    red[tid] = s;                        // len_b
    bfrag[0][tid * 8] = (short)0x3F80;   // P(0): one-hot at k=SOS=0, col tid
  }
  bar_lgkm();

  const int lenv = (int)(red[b] + 0.5f);
  float mxf = red[0];
  #pragma unroll
  for (int i = 1; i < 16; ++i) mxf = fmaxf(mxf, red[i]);
  const int tmax = (int)(mxf + 0.5f);

  // ---- h pipeline: ehc = exp(h(t)); raw1..raw3 = h(t+1..t+3) un-exp'd ----
  const float* hp = h + (size_t)(boff + b) * T * K + (16 * w + 4 * q);
  float4 ehc, raw1, raw2, raw3;
  {
    float4 r0 = *reinterpret_cast<const float4*>(hp);
    ehc  = make_float4(__expf(r0.x), __expf(r0.y), __expf(r0.z), __expf(r0.w));
    raw1 = *reinterpret_cast<const float4*>(hp + K);
    raw2 = *reinterpret_cast<const float4*>(hp + 2 * K);
    raw3 = *reinterpret_cast<const float4*>(hp + 3 * K);
  }

  // B-frag write slot for this lane's 4 output rows j = 16w+4q+0..3
  const int lw   = (2 * (w & 1) + (q >> 1)) * 16 + b;
  const int widx = ((w >> 1) * 64 + lw) * 8 + 4 * (q & 1);

  float S = 0.f;                  // shift of current P (per column b)
  unsigned pold0 = 0u, pold1 = 0u;

  for (int t = 0; t < tmax; ++t) {
    const int rp = t & 1;
    bar_lgkm();                                    // P(t), S' now visible

    const short8* bp = reinterpret_cast<const short8*>(&bfrag[rp][0]);
    short8 B0 = bp[0 * 64 + lane];
    short8 B1 = bp[1 * 64 + lane];
    short8 B2 = bp[2 * 64 + lane];
    short8 B3 = bp[3 * 64 + lane];
    const float Sp = S_lds[rp][b];                 // S_{t+1} (stale tracker)

    f32x4 C = {0.f, 0.f, 0.f, 0.f};
    C = __builtin_amdgcn_mfma_f32_16x16x32_bf16(A0, B0, C, 0, 0, 0);
    C = __builtin_amdgcn_mfma_f32_16x16x32_bf16(A1, B1, C, 0, 0, 0);
    C = __builtin_amdgcn_mfma_f32_16x16x32_bf16(A2, B2, C, 0, 0, 0);
    C = __builtin_amdgcn_mfma_f32_16x16x32_bf16(A3, B3, C, 0, 0, 0);

    const bool  act = (t < lenv);
    const float es  = __expf(S - Sp);              // exp(S_t - S_{t+1})

    float n0 = C[0] * ehc.x * es, n1 = C[1] * ehc.y * es;
    float n2 = C[2] * ehc.z * es, n3 = C[3] * ehc.w * es;
    unsigned w0 = bfpair(n0, n1), w1 = bfpair(n2, n3);
    w0 = act ? w0 : pold0;
    w1 = act ? w1 : pold1;
    pold0 = w0; pold1 = w1;
    *reinterpret_cast<int2*>(&bfrag[rp ^ 1][widx]) = make_int2((int)w0, (int)w1);

    // tracker: state j=2 = strip 0, q=0, reg 2; log(ehc.z) == h[b,t,2]
    if (w == 0 && q == 0) {
      float fs2 = S + __logf(C[2] * ehc.z);        // true score_2 after step t
      S_lds[rp ^ 1][b] = act ? fs2 : S;
    }
    S = act ? Sp : S;

    // rotate h pipeline: exp raw(t+1) (loaded >=1 iter ago), load raw(t+4)
    ehc  = make_float4(__expf(raw1.x), __expf(raw1.y), __expf(raw1.z), __expf(raw1.w));
    raw1 = raw2; raw2 = raw3;
    if (t + 4 < T)
      raw3 = *reinterpret_cast<const float4*>(hp + (size_t)(t + 4) * K);
  }

  // ---- epilogue: out[b] = sigma_b + log(sum_j P[j,b] * exp(trans[EOS,j])) ----
  if (w == 0 && q == 0) sigma[b] = S;
  bar_lgkm();
  const int rpf = tmax & 1;
  if (tid < 256) {
    const int bb = tid & 15, kg = tid >> 4;        // j-group: j = 8kg..8kg+7
    const int c = kg >> 2, ln = (kg & 3) * 16 + bb;
    const short8 pv = *reinterpret_cast<const short8*>(&bfrag[rpf][(c * 64 + ln) * 8]);
    const float* tre = trans + K + 8 * kg;         // trans[EOS=1][8kg..]
    float4 t0 = *reinterpret_cast<const float4*>(tre);
    float4 t1 = *reinterpret_cast<const float4*>(tre + 4);
    float acc = bf2f(pv[0]) * __expf(t0.x) + bf2f(pv[1]) * __expf(t0.y)
              + bf2f(pv[2]) * __expf(t0.z) + bf2f(pv[3]) * __expf(t0.w)
              + bf2f(pv[4]) * __expf(t1.x) + bf2f(pv[5]) * __expf(t1.y)
              + bf2f(pv[6]) * __expf(t1.z) + bf2f(pv[7]) * __expf(t1.w);
    red[bb * 16 + kg] = acc;
  }
  bar_lgkm();
  if (tid < NB) {
    float s = 0.f;
    #pragma unroll
    for (int i = 0; i < 16; ++i) s += red[tid * 16 + i];
    out[boff + tid] = sigma[tid] + __logf(s);
  }
}

extern "C" void kernel_launch(void* const* d_in, const int* in_sizes, int n_in,
                              void* d_out, int out_size, void* d_ws, size_t ws_size,
                              hipStream_t stream) {
  const float* h     = (const float*)d_in[0];  // (B,T,K) fp32
  const float* trans = (const float*)d_in[1];  // (K,K)   fp32
  const float* mask  = (const float*)d_in[2];  // (B,T)   fp32
  float* out = (float*)d_out;                  // (B,)    fp32
  const int B = in_sizes[0] / (T * K);         // 256
  crf_fwd<<<B / NB, 512, 0, stream>>>(h, trans, mask, out);
}

// Round 8
// 379.408 us; speedup vs baseline: 1.6339x; 1.2271x over previous
//
#include <hip/hip_runtime.h>

constexpr int K  = 128;  // states
constexpr int T  = 512;  // timesteps
constexpr int NB = 16;   // batch columns per block
constexpr int CH = 8;    // h chunk (timesteps) per DMA buffer

typedef __attribute__((ext_vector_type(8))) short short8;  // mfma A/B frag
typedef __attribute__((ext_vector_type(4))) float f32x4;   // mfma C/D frag

// s_barrier WITHOUT the compiler's vmcnt(0)-for-__syncthreads; LDS-only wait.
__device__ __forceinline__ void bar_lgkm() {
  asm volatile("s_waitcnt lgkmcnt(0)\n\ts_barrier" ::: "memory");
}
__device__ __forceinline__ void wait_vm0() {
  asm volatile("s_waitcnt vmcnt(0)" ::: "memory");
}
// async global -> LDS, 16B/lane; LDS dest = wave-uniform base + lane*16
__device__ __forceinline__ void dma16(const float* g, float* l) {
  __builtin_amdgcn_global_load_lds(
      (const __attribute__((address_space(1))) void*)g,
      (__attribute__((address_space(3))) void*)l, 16, 0, 0);
}
// pack two fp32 -> bf16x2 (round-half-up)
__device__ __forceinline__ unsigned bfpair(float a, float b) {
  unsigned ua = __float_as_uint(a) + 0x8000u;
  unsigned ub = __float_as_uint(b) + 0x8000u;
  return (ua >> 16) | (ub & 0xFFFF0000u);
}
__device__ __forceinline__ float bf2f(short v) {
  return __uint_as_float(((unsigned)(unsigned short)v) << 16);
}
union pk_u { int4 i; short8 s; };

// One block = 16 batch rows, 256 threads (4 waves). Wave w owns j-strips
// 2w, 2w+1 (rows 32w..32w+31). Per step: C_s(16x16) = E_s @ P (two
// interleaved 4-chains of mfma); P'[j,b] = C*exp(h)*exp(S_b - S'_b);
// per-column freeze at len_b. h delivered ONLY via global_load_lds chunk
// DMA (own-wave, no barrier dependence), vmcnt waited at chunk bounds.
__global__ __launch_bounds__(256, 1)
void crf_fwd(const float* __restrict__ h, const float* __restrict__ trans,
             const float* __restrict__ mask, float* __restrict__ out) {
  const int tid  = threadIdx.x;
  const int lane = tid & 63;
  const int w    = tid >> 6;       // wave id 0..3 -> strips 2w, 2w+1
  const int q    = lane >> 4;      // quad 0..3
  const int b    = lane & 15;      // batch column
  const int boff = blockIdx.x * NB;

  __shared__ __align__(16) short bfrag[2][4 * 64 * 8];  // [buf][(c*64+lane)*8+i]
  __shared__ __align__(16) float hch[2][CH][8][256];    // [buf][row][strip][64q+4b]
  __shared__ float S_lds[2][NB];
  __shared__ float sigma[NB];
  __shared__ float lenp[NB][8];
  __shared__ float red[NB * 16];

  // ---- A fragments for strips 2w+ss: elem i = exp(trans[16s+b][32c+8q+i])
  short8 A0[4], A1[4];
#define LDA(ss, c, dst) { \
    const float* rp_ = trans + (size_t)(16 * (2 * w + ss) + b) * K + 8 * q + 32 * c; \
    const float4* f4 = reinterpret_cast<const float4*>(rp_); \
    float4 x = f4[0], y = f4[1]; pk_u u; \
    u.i.x = bfpair(__expf(x.x), __expf(x.y)); \
    u.i.y = bfpair(__expf(x.z), __expf(x.w)); \
    u.i.z = bfpair(__expf(y.x), __expf(y.y)); \
    u.i.w = bfpair(__expf(y.z), __expf(y.w)); \
    dst = u.s; }
  LDA(0, 0, A0[0]) LDA(0, 1, A0[1]) LDA(0, 2, A0[2]) LDA(0, 3, A0[3])
  LDA(1, 0, A1[0]) LDA(1, 1, A1[1]) LDA(1, 2, A1[2]) LDA(1, 3, A1[3])
#undef LDA

  // ---- len partials ----
  if (tid < 128) {
    const int lb = tid >> 3, seg = tid & 7;
    const float4* mp = reinterpret_cast<const float4*>(
        mask + (size_t)(boff + lb) * T + seg * 64);
    float s = 0.f;
    #pragma unroll
    for (int i = 0; i < 16; ++i) { float4 v = mp[i]; s += (v.x + v.y) + (v.z + v.w); }
    lenp[lb][seg] = s;
  }
  // zero BOTH P buffers (256 threads x 2 x 16B = 8 KB)
  { int4 z = {0,0,0,0};
    reinterpret_cast<int4*>(&bfrag[0][0])[tid] = z;
    reinterpret_cast<int4*>(&bfrag[0][0])[tid + 256] = z; }
  if (tid < NB) { S_lds[0][tid] = 0.f; S_lds[1][tid] = 0.f; }
  bar_lgkm();
  if (tid < NB) {
    float s = 0.f;
    #pragma unroll
    for (int i = 0; i < 8; ++i) s += lenp[tid][i];
    red[tid] = s;                        // len_b
    bfrag[0][tid * 8] = (short)0x3F80;   // P(0): one-hot at k=SOS=0
  }
  bar_lgkm();

  const int lenv = (int)(red[b] + 0.5f);
  float mxf = red[0];
  #pragma unroll
  for (int i = 1; i < 16; ++i) mxf = fmaxf(mxf, red[i]);
  const int tmax = (int)(mxf + 0.5f);

  // ---- h chunk DMA: wave w loads its own strips; lane l=(16q+b) -> 16B ----
  const float* hb = h + (size_t)boff * T * K;
  const float* hsrc = hb + (size_t)b * T * K + 16 * (2 * w) + 4 * q;
#define ISSUE_CHUNK(t0, buf)                                        \
  { _Pragma("unroll")                                               \
    for (int r_ = 0; r_ < CH; ++r_) {                               \
      dma16(hsrc + (size_t)((t0) + r_) * K,      &hch[buf][r_][2*w][0]);   \
      dma16(hsrc + (size_t)((t0) + r_) * K + 16, &hch[buf][r_][2*w+1][0]); \
    } }
  ISSUE_CHUNK(0, 0)

  // B-frag write slots for strips 2w, 2w+1 (both land in chunk c = w)
  const int widx0 = (w * 64 + ((q >> 1)      * 16 + b)) * 8 + 4 * (q & 1);
  const int widx1 = (w * 64 + ((2 + (q >> 1)) * 16 + b)) * 8 + 4 * (q & 1);

  float S = 0.f;
  unsigned p00 = 0u, p01 = 0u, p10 = 0u, p11 = 0u;
  int cur = 0;

  for (int t = 0; t < tmax; ++t) {
    const int rp = t & 1;
    bar_lgkm();                                    // P(t), S' visible

    const int cpos = t & (CH - 1);
    if (cpos == 0) {                               // own-wave chunk resident
      wait_vm0();
      cur = (t >> 3) & 1;
      const int tn = t + CH;
      if (tn < tmax) ISSUE_CHUNK(tn, cur ^ 1)
    }

    // h for this step (own-wave LDS, no barrier needed)
    const int hidx = (q * 16 + b) * 4;
    float4 h0 = *reinterpret_cast<const float4*>(&hch[cur][cpos][2 * w][hidx]);
    float4 h1 = *reinterpret_cast<const float4*>(&hch[cur][cpos][2 * w + 1][hidx]);

    const short8* bp = reinterpret_cast<const short8*>(&bfrag[rp][0]);
    short8 B0 = bp[0 * 64 + lane];
    short8 B1 = bp[1 * 64 + lane];
    short8 B2 = bp[2 * 64 + lane];
    short8 B3 = bp[3 * 64 + lane];
    const float Sp = S_lds[rp][b];

    f32x4 C0 = {0.f,0.f,0.f,0.f}, C1 = {0.f,0.f,0.f,0.f};
    C0 = __builtin_amdgcn_mfma_f32_16x16x32_bf16(A0[0], B0, C0, 0, 0, 0);
    C1 = __builtin_amdgcn_mfma_f32_16x16x32_bf16(A1[0], B0, C1, 0, 0, 0);
    C0 = __builtin_amdgcn_mfma_f32_16x16x32_bf16(A0[1], B1, C0, 0, 0, 0);
    C1 = __builtin_amdgcn_mfma_f32_16x16x32_bf16(A1[1], B1, C1, 0, 0, 0);
    C0 = __builtin_amdgcn_mfma_f32_16x16x32_bf16(A0[2], B2, C0, 0, 0, 0);
    C1 = __builtin_amdgcn_mfma_f32_16x16x32_bf16(A1[2], B2, C1, 0, 0, 0);
    C0 = __builtin_amdgcn_mfma_f32_16x16x32_bf16(A0[3], B3, C0, 0, 0, 0);
    C1 = __builtin_amdgcn_mfma_f32_16x16x32_bf16(A1[3], B3, C1, 0, 0, 0);

    // exp(h) scheduled in the mfma shadow
    float4 e0 = make_float4(__expf(h0.x), __expf(h0.y), __expf(h0.z), __expf(h0.w));
    float4 e1 = make_float4(__expf(h1.x), __expf(h1.y), __expf(h1.z), __expf(h1.w));
    const bool  act = (t < lenv);
    const float es  = __expf(S - Sp);

    {
      unsigned w0 = bfpair(C0[0] * e0.x * es, C0[1] * e0.y * es);
      unsigned w1 = bfpair(C0[2] * e0.z * es, C0[3] * e0.w * es);
      w0 = act ? w0 : p00;  w1 = act ? w1 : p01;
      p00 = w0; p01 = w1;
      *reinterpret_cast<int2*>(&bfrag[rp ^ 1][widx0]) = make_int2((int)w0, (int)w1);
    }
    {
      unsigned w0 = bfpair(C1[0] * e1.x * es, C1[1] * e1.y * es);
      unsigned w1 = bfpair(C1[2] * e1.z * es, C1[3] * e1.w * es);
      w0 = act ? w0 : p10;  w1 = act ? w1 : p11;
      p10 = w0; p11 = w1;
      *reinterpret_cast<int2*>(&bfrag[rp ^ 1][widx1]) = make_int2((int)w0, (int)w1);
    }

    // tracker: state j=2 = strip 0 (wave 0), q=0, reg 2
    if (w == 0 && q == 0) {
      float fs2 = S + __logf(C0[2] * e0.z);        // true score_2 after step t
      S_lds[rp ^ 1][b] = act ? fs2 : S;
    }
    S = act ? Sp : S;
  }
#undef ISSUE_CHUNK

  // ---- epilogue: out[b] = sigma_b + log(sum_j P[j,b] * exp(trans[EOS,j])) ----
  if (w == 0 && q == 0) sigma[b] = S;
  bar_lgkm();
  const int rpf = tmax & 1;
  {
    const int bb = tid & 15, kg = tid >> 4;        // j-group: j = 8kg..8kg+7
    const int c = kg >> 2, ln = (kg & 3) * 16 + bb;
    const short8 pv = *reinterpret_cast<const short8*>(&bfrag[rpf][(c * 64 + ln) * 8]);
    const float* tre = trans + K + 8 * kg;         // trans[EOS=1][8kg..]
    float4 t0 = *reinterpret_cast<const float4*>(tre);
    float4 t1 = *reinterpret_cast<const float4*>(tre + 4);
    float acc = bf2f(pv[0]) * __expf(t0.x) + bf2f(pv[1]) * __expf(t0.y)
              + bf2f(pv[2]) * __expf(t0.z) + bf2f(pv[3]) * __expf(t0.w)
              + bf2f(pv[4]) * __expf(t1.x) + bf2f(pv[5]) * __expf(t1.y)
              + bf2f(pv[6]) * __expf(t1.z) + bf2f(pv[7]) * __expf(t1.w);
    red[bb * 16 + kg] = acc;
  }
  bar_lgkm();
  if (tid < NB) {
    float s = 0.f;
    #pragma unroll
    for (int i = 0; i < 16; ++i) s += red[tid * 16 + i];
    out[boff + tid] = sigma[tid] + __logf(s);
  }
}

extern "C" void kernel_launch(void* const* d_in, const int* in_sizes, int n_in,
                              void* d_out, int out_size, void* d_ws, size_t ws_size,
                              hipStream_t stream) {
  const float* h     = (const float*)d_in[0];  // (B,T,K) fp32
  const float* trans = (const float*)d_in[1];  // (K,K)   fp32
  const float* mask  = (const float*)d_in[2];  // (B,T)   fp32
  float* out = (float*)d_out;                  // (B,)    fp32
  const int B = in_sizes[0] / (T * K);         // 256
  crf_fwd<<<B / NB, 256, 0, stream>>>(h, trans, mask, out);
}